// Round 12
// baseline (190.661 us; speedup 1.0000x reference)
//
#include <hip/hip_runtime.h>
#include <hip/hip_bf16.h>
#include <stdint.h>

typedef __bf16 bf16;
typedef __bf16 bf16x4 __attribute__((ext_vector_type(4)));
typedef __bf16 bf16x8 __attribute__((ext_vector_type(8)));
typedef float f32x4 __attribute__((ext_vector_type(4)));

static constexpr int DIMM  = 1024;
static constexpr int NHEADS = 16;
static constexpr int HDIM  = 64;
static constexpr int SEQL  = 2048;
static constexpr int NB    = 4;
static constexpr int MTOT  = NB * SEQL;   // 8192
static constexpr float LOG2E = 1.4426950408889634f;

// XOR-swizzled byte offset within a [rows][64] bf16 LDS tile (row = 128 B = 8 x 16B)
__device__ __forceinline__ int swz(int row, int kc) {
    return row * 128 + ((kc ^ (row & 7)) << 4);
}

// async global->LDS, 16B per lane. LDS dest = wave-uniform base + lane*16.
__device__ __forceinline__ void gl_lds16(const void* g, void* l) {
    __builtin_amdgcn_global_load_lds(
        (const __attribute__((address_space(1))) unsigned int*)g,
        (__attribute__((address_space(3))) unsigned int*)l,
        16, 0, 0);
}

__device__ __forceinline__ bf16x8 cvt8(f32x4 a, f32x4 b) {
    bf16x8 r;
    r[0] = (bf16)a[0]; r[1] = (bf16)a[1]; r[2] = (bf16)a[2]; r[3] = (bf16)a[3];
    r[4] = (bf16)b[0]; r[5] = (bf16)b[1]; r[6] = (bf16)b[2]; r[7] = (bf16)b[3];
    return r;
}

// ---------------------------------------------------------------------------
// Kernel 0: weight dtype conversion.  Wq, Wk, Wv, Wo (fp32) -> bf16 in ws.
// ---------------------------------------------------------------------------
__global__ __launch_bounds__(256)
void cvt_kernel(const float* __restrict__ Wq, const float* __restrict__ Wk,
                const float* __restrict__ Wv, const float* __restrict__ Wo,
                bf16* __restrict__ Wqb, bf16* __restrict__ Wkb,
                bf16* __restrict__ Wvb, bf16* __restrict__ Wob)
{
    const size_t NW = (size_t)DIMM * DIMM;          // 1048576 = 1<<20
    size_t i = ((size_t)blockIdx.x * 256 + threadIdx.x) * 8;
    int wsel = (int)(i >> 20);
    size_t off = i & (NW - 1);
    const float* src; bf16* dst;
    if      (wsel == 0) { src = Wq; dst = Wqb; }
    else if (wsel == 1) { src = Wk; dst = Wkb; }
    else if (wsel == 2) { src = Wv; dst = Wvb; }
    else                { src = Wo; dst = Wob; }
    f32x4 a = *(const f32x4*)(src + off);
    f32x4 b = *(const f32x4*)(src + off + 4);
    *(bf16x8*)(dst + off) = cvt8(a, b);
}

// ---------------------------------------------------------------------------
// Kernel 1: fused QKV projection + RoPE + V-transpose.
// A = x staged FP32 via gl_lds (XOR involution, cvt at fragment read);
// B = 3 bf16 weights (folded 128x32 layout). BK=32 double-buffered,
// counted vmcnt(10), raw barriers, setprio. LDS 80 KB -> 2 blocks/CU.
// XCD-aware flat grid: bn = bid&7 (one B-panel per XCD), bm = bid>>3.
// ---------------------------------------------------------------------------
__global__ __launch_bounds__(256, 2)
void qkv_kernel(const float* __restrict__ xf,
                const bf16* __restrict__ Wqb, const bf16* __restrict__ Wkb,
                const bf16* __restrict__ Wvb,
                const float* __restrict__ cosT, const float* __restrict__ sinT,
                bf16* __restrict__ qb, bf16* __restrict__ kb, bf16* __restrict__ vTb)
{
    __shared__ __align__(16) float AsF[2][128 * 32];   // 32 KB
    __shared__ __align__(16) bf16  Bq[2][128 * 32];    // 16 KB each
    __shared__ __align__(16) bf16  Bk[2][128 * 32];
    __shared__ __align__(16) bf16  Bv[2][128 * 32];

    const int bid = (int)blockIdx.x;
    const int bn  = (bid & 7) * 128;
    const int bm  = (bid >> 3) * 128;

    const int tid  = threadIdx.x;
    const int lane = tid & 63;
    const int w    = tid >> 6;
    const int l15  = lane & 15;
    const int lg   = lane >> 4;
    const int l7   = l15 & 7;
    const int wm   = (w >> 1) * 64;
    const int wn   = (w & 1) * 64;

    f32x4 acc[3][4][4];
    #pragma unroll
    for (int w3 = 0; w3 < 3; ++w3)
        #pragma unroll
        for (int mf = 0; mf < 4; ++mf)
            #pragma unroll
            for (int nf = 0; nf < 4; ++nf)
                acc[w3][mf][nf] = f32x4{0.f, 0.f, 0.f, 0.f};

    // ---- B staging geometry (verified r8): wave w stages chunks 2w,2w+1 ----
    const int c0  = w * 2;
    const int rp0 = lane >> 3;              // 0..7
    const int ttb = (lane & 7) ^ rp0;       // logical kc8 for B
    const int rgo = (ttb >> 2) << 6;        // +64 rows if kc8 >= 4
    const int kqb = (ttb & 3) * 8;          // B k-offset within 32

    // ---- A (fp32) staging geometry: wave w stages chunks 4w..4w+3 ----
    const int ca0 = w * 4;
    const int kqa = ((lane & 7) ^ rp0) * 4; // f32 col offset (chunk involution)

    auto stage = [&](int t, int buf) {
        const int k0 = t * 32;
        #pragma unroll
        for (int i = 0; i < 4; ++i) {       // A: 4 x 1KB chunks (8 rows x 128B)
            const int c = ca0 + i;
            gl_lds16(xf + (size_t)(bm + c * 8 + rp0) * DIMM + k0 + kqa,
                     &AsF[buf][c * 256]);
        }
        #pragma unroll
        for (int i = 0; i < 2; ++i) {       // B: 2 chunks per matrix
            const int c  = c0 + i;
            const int rg = c * 8 + rp0 + rgo;
            const size_t an = (size_t)(bn + rg) * DIMM + k0 + kqb;
            gl_lds16(Wqb + an, &Bq[buf][c * 512]);
            gl_lds16(Wkb + an, &Bk[buf][c * 512]);
            gl_lds16(Wvb + an, &Bv[buf][c * 512]);
        }
    };

    auto rdB = [&](const bf16* base, int row) {
        return *(const bf16x8*)((const char*)base +
            (row & 63) * 128 + (((((row >> 6) << 2) | lg) ^ (row & 7)) << 4));
    };

    auto compute = [&](int buf) {
        bf16x8 af[4];
        #pragma unroll
        for (int mf = 0; mf < 4; ++mf) {
            const int row = wm + mf * 16 + l15;   // row&7 == l7
            const char* rb = (const char*)AsF[buf] + row * 128;
            f32x4 a0 = *(const f32x4*)(rb + (((2 * lg    ) ^ l7) << 4));
            f32x4 a1 = *(const f32x4*)(rb + (((2 * lg + 1) ^ l7) << 4));
            af[mf] = cvt8(a0, a1);
        }
        const bf16* bsel[3] = {Bq[buf], Bk[buf], Bv[buf]};
        __builtin_amdgcn_s_setprio(1);
        #pragma unroll
        for (int w3 = 0; w3 < 3; ++w3) {
            bf16x8 bfr[4];
            #pragma unroll
            for (int nf = 0; nf < 4; ++nf)
                bfr[nf] = rdB(bsel[w3], wn + nf * 16 + l15);
            #pragma unroll
            for (int mf = 0; mf < 4; ++mf)
                #pragma unroll
                for (int nf = 0; nf < 4; ++nf)
                    acc[w3][mf][nf] = __builtin_amdgcn_mfma_f32_16x16x32_bf16(
                        af[mf], bfr[nf], acc[w3][mf][nf], 0, 0, 0);
        }
        __builtin_amdgcn_s_setprio(0);
    };

    stage(0, 0);
    #pragma unroll 1
    for (int t = 0; t < 31; ++t) {
        stage(t + 1, (t + 1) & 1);
        asm volatile("s_waitcnt vmcnt(10)" ::: "memory");  // retire stage(t) only
        __builtin_amdgcn_s_barrier();
        __builtin_amdgcn_sched_barrier(0);
        compute(t & 1);
        __builtin_amdgcn_sched_barrier(0);
        __builtin_amdgcn_s_barrier();
    }
    asm volatile("s_waitcnt vmcnt(0)" ::: "memory");
    __builtin_amdgcn_s_barrier();
    __builtin_amdgcn_sched_barrier(0);
    compute(1);

    // ---- epilogue: RoPE for q,k (shared tables), transpose-store v ----
    #pragma unroll
    for (int mf = 0; mf < 4; ++mf) {
        #pragma unroll
        for (int nf = 0; nf < 4; ++nf) {
            int n = bn + wn + nf * 16 + l15;
            int h = n >> 6;
            int d = n & 63;
            float sign = (d < 32) ? -1.f : 1.f;
            #pragma unroll
            for (int r = 0; r < 4; ++r) {
                int m = bm + wm + mf * 16 + lg * 4 + r;
                int b = m >> 11, s = m & 2047;
                float c  = cosT[s * 64 + d];
                float sv = sinT[s * 64 + d];
                size_t o_qk = ((size_t)((b * NHEADS + h) * SEQL + s)) * HDIM + d;
                float q0 = acc[0][mf][nf][r], q1 = acc[0][mf][nf ^ 2][r];
                float k0v = acc[1][mf][nf][r], k1 = acc[1][mf][nf ^ 2][r];
                qb[o_qk] = (bf16)((q0 * c + sign * q1 * sv) * (0.125f * LOG2E));
                kb[o_qk] = (bf16)(k0v * c + sign * k1 * sv);
                vTb[((size_t)((b * NHEADS + h) * HDIM + d)) * SEQL + s] = (bf16)acc[2][mf][nf][r];
            }
        }
    }
}

// ---------------------------------------------------------------------------
// Kernel 2: causal flash attention — swapped-QK^T orientation.
// P addressing identical to r10 (proven). L via ones-MFMA (matrix pipe):
// no VALU row-sum, no epilogue shuffles.
// ---------------------------------------------------------------------------
__global__ __launch_bounds__(256, 3)
void attn_kernel(bf16* __restrict__ qb, const bf16* __restrict__ kb,
                 const bf16* __restrict__ vTb)
{
    __shared__ __align__(16) bf16 Ks[2][64 * 64];
    __shared__ __align__(16) bf16 Vs[2][64 * 64];
    __shared__ __align__(16) bf16 Pl[4][32 * 64];   // per-wave P^T[q][kv]

    const int bh  = blockIdx.x;
    const int qt  = 15 - (int)blockIdx.y;
    const int tid = threadIdx.x;
    const int lane = tid & 63, w = tid >> 6;
    const int l15 = lane & 15, lg = lane >> 4;

    bf16*       Qp = qb  + (size_t)bh * SEQL * HDIM;
    const bf16* Kp = kb  + (size_t)bh * SEQL * HDIM;
    const bf16* Vp = vTb + (size_t)bh * HDIM * SEQL;

    const int q0  = qt * 128 + w * 32;
    const int njt = 2 * qt + 2;

    // Q B-fragments (pre-scaled by 0.125*log2e): [mf][ks]
    bf16x8 qf[2][2];
    #pragma unroll
    for (int mf = 0; mf < 2; ++mf)
        #pragma unroll
        for (int ks = 0; ks < 2; ++ks)
            qf[mf][ks] = *(const bf16x8*)(Qp + (size_t)(q0 + mf * 16 + l15) * HDIM + ks * 32 + lg * 8);

    bf16x8 ones;
    #pragma unroll
    for (int e = 0; e < 8; ++e) ones[e] = (bf16)1.0f;

    f32x4 oacc[4][2];          // [nd][mf] : O^T fragments (row=d, col=q)
    f32x4 lacc[2];             // L[q=l15] via ones-MFMA (all acc rows equal)
    #pragma unroll
    for (int mf = 0; mf < 2; ++mf) lacc[mf] = f32x4{0.f, 0.f, 0.f, 0.f};
    #pragma unroll
    for (int nd = 0; nd < 4; ++nd)
        #pragma unroll
        for (int mf = 0; mf < 2; ++mf)
            oacc[nd][mf] = f32x4{0.f, 0.f, 0.f, 0.f};

    char* Pw = (char*)Pl[w];
    const int l7 = l15 & 7;
    const int srow0 = tid >> 3;
    const int skc   = tid & 7;

    bf16x8 kr[2], vr[2];
    auto issue = [&](int j) {
        const int kk0 = j * 64;
        #pragma unroll
        for (int c = 0; c < 2; ++c) {
            int row = c * 32 + srow0;
            kr[c] = *(const bf16x8*)(Kp + (size_t)(kk0 + row) * HDIM + skc * 8);
            vr[c] = *(const bf16x8*)(Vp + (size_t)row * SEQL + kk0 + skc * 8);
        }
    };
    auto commit = [&](int b) {
        #pragma unroll
        for (int c = 0; c < 2; ++c) {
            int row = c * 32 + srow0;
            *(bf16x8*)((char*)Ks[b] + swz(row, skc)) = kr[c];
            *(bf16x8*)((char*)Vs[b] + swz(row, skc)) = vr[c];
        }
    };

    issue(0);
    commit(0);
    __syncthreads();

    for (int j = 0; j < njt; ++j) {
        const int kk0 = j * 64;
        const int buf = j & 1;
        const bool more = (j + 1 < njt);
        if (more) issue(j + 1);

        // ---- S^T = K Q^T : sacc[nf][mf], row=kv, col=q ----
        f32x4 sacc[4][2];
        #pragma unroll
        for (int nf = 0; nf < 4; ++nf)
            #pragma unroll
            for (int mf = 0; mf < 2; ++mf)
                sacc[nf][mf] = f32x4{0.f, 0.f, 0.f, 0.f};
        #pragma unroll
        for (int ks = 0; ks < 2; ++ks) {
            bf16x8 kf[4];
            #pragma unroll
            for (int nf = 0; nf < 4; ++nf)
                kf[nf] = *(const bf16x8*)((const char*)Ks[buf] + swz(nf * 16 + l15, ks * 4 + lg));
            #pragma unroll
            for (int nf = 0; nf < 4; ++nf)
                #pragma unroll
                for (int mf = 0; mf < 2; ++mf)
                    sacc[nf][mf] = __builtin_amdgcn_mfma_f32_16x16x32_bf16(
                        kf[nf], qf[mf][ks], sacc[nf][mf], 0, 0, 0);
        }

        // ---- P = exp2(S), mask, b64 write (r10 addressing, proven) ----
        const bool nm = (kk0 + 63 > q0);
        #pragma unroll
        for (int nf = 0; nf < 4; ++nf) {
            #pragma unroll
            for (int mf = 0; mf < 2; ++mf) {
                bf16x4 pb;
                #pragma unroll
                for (int r = 0; r < 4; ++r) {
                    float s = sacc[nf][mf][r];
                    if (nm) {
                        int kv = kk0 + nf * 16 + lg * 4 + r;
                        int qq = q0 + mf * 16 + l15;
                        if (kv > qq) s = -1.0e30f;
                    }
                    pb[r] = (bf16)exp2f(s);
                }
                *(bf16x4*)(Pw + (mf * 16 + l15) * 128
                              + (((2 * nf + (lg >> 1)) ^ l7) << 4) + (lg & 1) * 8) = pb;
            }
        }

        // ---- O^T += V^T P^T ; L += 1^T P^T (both matrix pipe) ----
        #pragma unroll
        for (int ks = 0; ks < 2; ++ks) {
            bf16x8 pf[2], vf[4];
            #pragma unroll
            for (int mf = 0; mf < 2; ++mf)
                pf[mf] = *(const bf16x8*)(Pw + (mf * 16 + l15) * 128
                                             + (((ks * 4 + lg) ^ l7) << 4));
            #pragma unroll
            for (int nd = 0; nd < 4; ++nd)
                vf[nd] = *(const bf16x8*)((const char*)Vs[buf] + swz(nd * 16 + l15, ks * 4 + lg));
            #pragma unroll
            for (int mf = 0; mf < 2; ++mf)
                lacc[mf] = __builtin_amdgcn_mfma_f32_16x16x32_bf16(
                    ones, pf[mf], lacc[mf], 0, 0, 0);
            #pragma unroll
            for (int nd = 0; nd < 4; ++nd)
                #pragma unroll
                for (int mf = 0; mf < 2; ++mf)
                    oacc[nd][mf] = __builtin_amdgcn_mfma_f32_16x16x32_bf16(
                        vf[nd], pf[mf], oacc[nd][mf], 0, 0, 0);
        }

        if (more) {
            commit(buf ^ 1);
            __syncthreads();
        }
    }

    // ---- epilogue: O = O^T / L (L[q] = lacc[mf][0], rows all equal) ----
    float inv[2] = {1.f / lacc[0][0], 1.f / lacc[1][0]};
    #pragma unroll
    for (int nd = 0; nd < 4; ++nd)
        #pragma unroll
        for (int mf = 0; mf < 2; ++mf) {
            bf16x4 o4;
            #pragma unroll
            for (int r = 0; r < 4; ++r)
                o4[r] = (bf16)(oacc[nd][mf][r] * inv[mf]);
            int s = q0 + mf * 16 + l15;
            int d = nd * 16 + lg * 4;
            *(bf16x4*)(Qp + (size_t)s * HDIM + d) = o4;
        }
}

// ---------------------------------------------------------------------------
// Kernel 3: output projection  out(f32) = O @ Wo^T  (r9 structure, kept).
// ---------------------------------------------------------------------------
__global__ __launch_bounds__(256, 2)
void oproj_kernel(const bf16* __restrict__ O, const bf16* __restrict__ Wob,
                  float* __restrict__ outp)
{
    __shared__ __align__(16) bf16 Bs[2][128 * 32];

    const int bm = (int)blockIdx.x * 128;
    const int bn = (int)blockIdx.y * 128;

    const int tid  = threadIdx.x;
    const int lane = tid & 63;
    const int w    = tid >> 6;
    const int l15  = lane & 15;
    const int lg   = lane >> 4;
    const int wm   = (w >> 1) * 64;
    const int wn   = (w & 1) * 64;

    f32x4 acc[4][4];
    #pragma unroll
    for (int mf = 0; mf < 4; ++mf)
        #pragma unroll
        for (int nf = 0; nf < 4; ++nf)
            acc[mf][nf] = f32x4{0.f, 0.f, 0.f, 0.f};

    const int c0  = w * 2;
    const int rp0 = lane >> 3;
    const int tt  = (lane & 7) ^ rp0;
    const int rgo = (tt >> 2) << 6;
    const int kq  = (tt & 3) * 8;

    auto stageB = [&](int t, int buf) {
        const int k0 = t * 32;
        #pragma unroll
        for (int i = 0; i < 2; ++i) {
            const int c  = c0 + i;
            const int rg = c * 8 + rp0 + rgo;
            gl_lds16(Wob + (size_t)(bn + rg) * DIMM + k0 + kq, &Bs[buf][c * 512]);
        }
    };

    auto loadA = [&](bf16x8 (&dst)[4], int t) {
        const int k0 = t * 32;
        #pragma unroll
        for (int mf = 0; mf < 4; ++mf) {
            int m = bm + wm + mf * 16 + l15;
            int b = m >> 11, s = m & 2047;
            int k = k0 + lg * 8;
            int h = k >> 6, dd = k & 63;
            dst[mf] = *(const bf16x8*)(O + ((size_t)((b * NHEADS + h) * SEQL + s)) * HDIM + dd);
        }
    };

    auto rd = [&](const bf16* base, int row) {
        return *(const bf16x8*)((const char*)base +
            (row & 63) * 128 + (((((row >> 6) << 2) | lg) ^ (row & 7)) << 4));
    };

    auto compute = [&](int buf, const bf16x8 (&af)[4]) {
        bf16x8 bfr[4];
        #pragma unroll
        for (int nf = 0; nf < 4; ++nf)
            bfr[nf] = rd(Bs[buf], wn + nf * 16 + l15);
        #pragma unroll
        for (int mf = 0; mf < 4; ++mf)
            #pragma unroll
            for (int nf = 0; nf < 4; ++nf)
                acc[mf][nf] = __builtin_amdgcn_mfma_f32_16x16x32_bf16(
                    af[mf], bfr[nf], acc[mf][nf], 0, 0, 0);
    };

    bf16x8 aA[4], aB[4];

    stageB(0, 0);
    __builtin_amdgcn_sched_barrier(0);
    loadA(aA, 0);
    __builtin_amdgcn_sched_barrier(0);

    // outstanding at wait = B(t)2 + A(t)4 + B(t+1)2 = 8 -> vmcnt(6) retires B(t)
    auto step = [&](bf16x8 (&cur)[4], bf16x8 (&nxt)[4], int t) {
        stageB(t + 1, (t + 1) & 1);
        __builtin_amdgcn_sched_barrier(0);
        asm volatile("s_waitcnt vmcnt(6)" ::: "memory");
        __builtin_amdgcn_s_barrier();
        __builtin_amdgcn_sched_barrier(0);
        loadA(nxt, t + 1);
        compute(t & 1, cur);
        __builtin_amdgcn_sched_barrier(0);
        __builtin_amdgcn_s_barrier();
    };

    #pragma unroll 1
    for (int tp = 0; tp < 15; ++tp) {
        step(aA, aB, 2 * tp);
        step(aB, aA, 2 * tp + 1);
    }
    step(aA, aB, 30);
    asm volatile("s_waitcnt vmcnt(0)" ::: "memory");
    __builtin_amdgcn_s_barrier();
    __builtin_amdgcn_sched_barrier(0);
    compute(1, aB);

    #pragma unroll
    for (int mf = 0; mf < 4; ++mf)
        #pragma unroll
        for (int nf = 0; nf < 4; ++nf) {
            int n = bn + wn + nf * 16 + l15;
            #pragma unroll
            for (int r = 0; r < 4; ++r) {
                int m = bm + wm + mf * 16 + lg * 4 + r;
                outp[(size_t)m * DIMM + n] = acc[mf][nf][r];
            }
        }
}

// ---------------------------------------------------------------------------
extern "C" void kernel_launch(void* const* d_in, const int* in_sizes, int n_in,
                              void* d_out, int out_size, void* d_ws, size_t ws_size,
                              hipStream_t stream)
{
    const float* x    = (const float*)d_in[0];
    const float* Wq   = (const float*)d_in[1];
    const float* Wk   = (const float*)d_in[2];
    const float* Wv   = (const float*)d_in[3];
    const float* Wo   = (const float*)d_in[4];
    const float* cosT = (const float*)d_in[5];
    const float* sinT = (const float*)d_in[6];

    const size_t NELEM = (size_t)MTOT * DIMM;   // 8.39M
    const size_t NW    = (size_t)DIMM * DIMM;   // 1.05M
    bf16* qb  = (bf16*)d_ws;          // 16.8 MB (becomes O after attn)
    bf16* kb  = qb + NELEM;           // 16.8 MB
    bf16* vT  = kb + NELEM;           // 16.8 MB
    bf16* Wqb = vT + NELEM;           // 2.1 MB each
    bf16* Wkb = Wqb + NW;
    bf16* Wvb = Wkb + NW;
    bf16* Wob = Wvb + NW;             // high-water: 58.7 MB

    dim3 blk(256);
    cvt_kernel<<<dim3(2048), blk, 0, stream>>>(Wq, Wk, Wv, Wo, Wqb, Wkb, Wvb, Wob);

    qkv_kernel<<<dim3(512), blk, 0, stream>>>(x, Wqb, Wkb, Wvb, cosT, sinT,
                                              qb, kb, vT);

    dim3 g2(NB * NHEADS, SEQL / 128);
    attn_kernel<<<g2, blk, 0, stream>>>(qb, kb, vT);

    dim3 g3(MTOT / 128, DIMM / 128);
    oproj_kernel<<<g3, blk, 0, stream>>>(qb, Wob, (float*)d_out);
}

// Round 13
// 174.689 us; speedup vs baseline: 1.0914x; 1.0914x over previous
//
#include <hip/hip_runtime.h>
#include <hip/hip_bf16.h>
#include <stdint.h>

typedef __bf16 bf16;
typedef __bf16 bf16x4 __attribute__((ext_vector_type(4)));
typedef __bf16 bf16x8 __attribute__((ext_vector_type(8)));
typedef float f32x4 __attribute__((ext_vector_type(4)));

static constexpr int DIMM  = 1024;
static constexpr int NHEADS = 16;
static constexpr int HDIM  = 64;
static constexpr int SEQL  = 2048;
static constexpr int NB    = 4;
static constexpr int MTOT  = NB * SEQL;   // 8192
static constexpr float LOG2E = 1.4426950408889634f;

// XOR-swizzled byte offset within a [rows][64] bf16 LDS tile (row = 128 B = 8 x 16B)
__device__ __forceinline__ int swz(int row, int kc) {
    return row * 128 + ((kc ^ (row & 7)) << 4);
}

// async global->LDS, 16B per lane. LDS dest = wave-uniform base + lane*16.
__device__ __forceinline__ void gl_lds16(const void* g, void* l) {
    __builtin_amdgcn_global_load_lds(
        (const __attribute__((address_space(1))) unsigned int*)g,
        (__attribute__((address_space(3))) unsigned int*)l,
        16, 0, 0);
}

__device__ __forceinline__ bf16x8 cvt8(f32x4 a, f32x4 b) {
    bf16x8 r;
    r[0] = (bf16)a[0]; r[1] = (bf16)a[1]; r[2] = (bf16)a[2]; r[3] = (bf16)a[3];
    r[4] = (bf16)b[0]; r[5] = (bf16)b[1]; r[6] = (bf16)b[2]; r[7] = (bf16)b[3];
    return r;
}

// ---------------------------------------------------------------------------
// Kernel 0: dtype conversion.  x, Wq, Wk, Wv, Wo (fp32) -> bf16 in ws.
// (x MUST be bf16 for qkv: A is the streamed operand — r12 showed fp32-A
//  doubles per-XCD L2 fill traffic and costs ~32 µs.)
// ---------------------------------------------------------------------------
__global__ __launch_bounds__(256)
void cvt_kernel(const float* __restrict__ x,  const float* __restrict__ Wq,
                const float* __restrict__ Wk, const float* __restrict__ Wv,
                const float* __restrict__ Wo,
                bf16* __restrict__ xb,  bf16* __restrict__ Wqb,
                bf16* __restrict__ Wkb, bf16* __restrict__ Wvb,
                bf16* __restrict__ Wob)
{
    const size_t NX = (size_t)MTOT * DIMM;          // 8388608
    const size_t NW = (size_t)DIMM * DIMM;          // 1048576 = 1<<20
    size_t i = ((size_t)blockIdx.x * 256 + threadIdx.x) * 8;
    const float* src; bf16* dst; size_t off;
    if (i < NX) { src = x; dst = xb; off = i; }
    else {
        size_t j = i - NX;
        int wsel = (int)(j >> 20);
        off = j & (NW - 1);
        if      (wsel == 0) { src = Wq; dst = Wqb; }
        else if (wsel == 1) { src = Wk; dst = Wkb; }
        else if (wsel == 2) { src = Wv; dst = Wvb; }
        else                { src = Wo; dst = Wob; }
    }
    f32x4 a = *(const f32x4*)(src + off);
    f32x4 b = *(const f32x4*)(src + off + 4);
    *(bf16x8*)(dst + off) = cvt8(a, b);
}

// ---------------------------------------------------------------------------
// Kernel 1: fused QKV projection + RoPE + V-transpose (r10 version, proven).
// BK=32 double-buffered gl_lds staging, counted vmcnt(8), raw barriers,
// folded 128x32 LDS layout with XOR swizzle, s_setprio around MFMA cluster.
// XCD-aware grid: flat bid, bn = bid&7 (one B-panel per XCD), bm = bid>>3.
// ---------------------------------------------------------------------------
__global__ __launch_bounds__(256, 2)
void qkv_kernel(const bf16* __restrict__ xb,
                const bf16* __restrict__ Wqb, const bf16* __restrict__ Wkb,
                const bf16* __restrict__ Wvb,
                const float* __restrict__ cosT, const float* __restrict__ sinT,
                bf16* __restrict__ qb, bf16* __restrict__ kb, bf16* __restrict__ vTb)
{
    __shared__ __align__(16) bf16 As[2][128 * 32];
    __shared__ __align__(16) bf16 Bq[2][128 * 32];
    __shared__ __align__(16) bf16 Bk[2][128 * 32];
    __shared__ __align__(16) bf16 Bv[2][128 * 32];

    const int bid = (int)blockIdx.x;
    const int bn  = (bid & 7) * 128;      // XCD (bid%8) owns bn-panel
    const int bm  = (bid >> 3) * 128;

    const int tid  = threadIdx.x;
    const int lane = tid & 63;
    const int w    = tid >> 6;
    const int l15  = lane & 15;
    const int lg   = lane >> 4;
    const int wm   = (w >> 1) * 64;
    const int wn   = (w & 1) * 64;

    f32x4 acc[3][4][4];
    #pragma unroll
    for (int w3 = 0; w3 < 3; ++w3)
        #pragma unroll
        for (int mf = 0; mf < 4; ++mf)
            #pragma unroll
            for (int nf = 0; nf < 4; ++nf)
                acc[w3][mf][nf] = f32x4{0.f, 0.f, 0.f, 0.f};

    // staging geometry (verified r8): wave handles chunks c0, c0+1 per tile
    const int c0  = w * 2;
    const int rp0 = lane >> 3;              // phys row within chunk 0..7
    const int tt  = (lane & 7) ^ rp0;       // logical kc8
    const int rgo = (tt >> 2) << 6;         // +64 rows if kc8 >= 4
    const int kq  = (tt & 3) * 8;           // k-offset within 32

    auto stage = [&](int t, int buf) {
        const int k0 = t * 32;
        #pragma unroll
        for (int i = 0; i < 2; ++i) {
            const int c  = c0 + i;
            const int rg = c * 8 + rp0 + rgo;
            const size_t am = (size_t)(bm + rg) * DIMM + k0 + kq;
            const size_t an = (size_t)(bn + rg) * DIMM + k0 + kq;
            gl_lds16(xb  + am, &As[buf][c * 512]);
            gl_lds16(Wqb + an, &Bq[buf][c * 512]);
            gl_lds16(Wkb + an, &Bk[buf][c * 512]);
            gl_lds16(Wvb + an, &Bv[buf][c * 512]);
        }
    };

    auto rd = [&](const bf16* base, int row) {
        return *(const bf16x8*)((const char*)base +
            (row & 63) * 128 + (((((row >> 6) << 2) | lg) ^ (row & 7)) << 4));
    };

    auto compute = [&](int buf) {
        bf16x8 af[4];
        #pragma unroll
        for (int mf = 0; mf < 4; ++mf)
            af[mf] = rd(As[buf], wm + mf * 16 + l15);
        const bf16* bsel[3] = {Bq[buf], Bk[buf], Bv[buf]};
        __builtin_amdgcn_s_setprio(1);
        #pragma unroll
        for (int w3 = 0; w3 < 3; ++w3) {
            bf16x8 bfr[4];
            #pragma unroll
            for (int nf = 0; nf < 4; ++nf)
                bfr[nf] = rd(bsel[w3], wn + nf * 16 + l15);
            #pragma unroll
            for (int mf = 0; mf < 4; ++mf)
                #pragma unroll
                for (int nf = 0; nf < 4; ++nf)
                    acc[w3][mf][nf] = __builtin_amdgcn_mfma_f32_16x16x32_bf16(
                        af[mf], bfr[nf], acc[w3][mf][nf], 0, 0, 0);
        }
        __builtin_amdgcn_s_setprio(0);
    };

    stage(0, 0);
    #pragma unroll 1
    for (int t = 0; t < 31; ++t) {
        stage(t + 1, (t + 1) & 1);
        asm volatile("s_waitcnt vmcnt(8)" ::: "memory");   // wait stage(t) only
        __builtin_amdgcn_s_barrier();
        __builtin_amdgcn_sched_barrier(0);
        compute(t & 1);
        __builtin_amdgcn_sched_barrier(0);
        __builtin_amdgcn_s_barrier();
    }
    asm volatile("s_waitcnt vmcnt(0)" ::: "memory");
    __builtin_amdgcn_s_barrier();
    __builtin_amdgcn_sched_barrier(0);
    compute(1);

    // ---- epilogue: RoPE for q,k (shared tables), transpose-store v ----
    #pragma unroll
    for (int mf = 0; mf < 4; ++mf) {
        #pragma unroll
        for (int nf = 0; nf < 4; ++nf) {
            int n = bn + wn + nf * 16 + l15;
            int h = n >> 6;
            int d = n & 63;
            float sign = (d < 32) ? -1.f : 1.f;
            #pragma unroll
            for (int r = 0; r < 4; ++r) {
                int m = bm + wm + mf * 16 + lg * 4 + r;
                int b = m >> 11, s = m & 2047;
                float c  = cosT[s * 64 + d];
                float sv = sinT[s * 64 + d];
                size_t o_qk = ((size_t)((b * NHEADS + h) * SEQL + s)) * HDIM + d;
                float q0 = acc[0][mf][nf][r], q1 = acc[0][mf][nf ^ 2][r];
                float k0v = acc[1][mf][nf][r], k1 = acc[1][mf][nf ^ 2][r];
                qb[o_qk] = (bf16)((q0 * c + sign * q1 * sv) * (0.125f * LOG2E));
                kb[o_qk] = (bf16)(k0v * c + sign * k1 * sv);
                vTb[((size_t)((b * NHEADS + h) * HDIM + d)) * SEQL + s] = (bf16)acc[2][mf][nf][r];
            }
        }
    }
}

// ---------------------------------------------------------------------------
// Kernel 2: causal flash attention — swapped-QK^T orientation (r12 version).
// P addressing identical to r10 (proven). L via ones-MFMA (matrix pipe):
// no VALU row-sum, no epilogue shuffles.
// ---------------------------------------------------------------------------
__global__ __launch_bounds__(256, 3)
void attn_kernel(bf16* __restrict__ qb, const bf16* __restrict__ kb,
                 const bf16* __restrict__ vTb)
{
    __shared__ __align__(16) bf16 Ks[2][64 * 64];
    __shared__ __align__(16) bf16 Vs[2][64 * 64];
    __shared__ __align__(16) bf16 Pl[4][32 * 64];   // per-wave P^T[q][kv]

    const int bh  = blockIdx.x;
    const int qt  = 15 - (int)blockIdx.y;
    const int tid = threadIdx.x;
    const int lane = tid & 63, w = tid >> 6;
    const int l15 = lane & 15, lg = lane >> 4;

    bf16*       Qp = qb  + (size_t)bh * SEQL * HDIM;
    const bf16* Kp = kb  + (size_t)bh * SEQL * HDIM;
    const bf16* Vp = vTb + (size_t)bh * HDIM * SEQL;

    const int q0  = qt * 128 + w * 32;
    const int njt = 2 * qt + 2;

    // Q B-fragments (pre-scaled by 0.125*log2e): [mf][ks]
    bf16x8 qf[2][2];
    #pragma unroll
    for (int mf = 0; mf < 2; ++mf)
        #pragma unroll
        for (int ks = 0; ks < 2; ++ks)
            qf[mf][ks] = *(const bf16x8*)(Qp + (size_t)(q0 + mf * 16 + l15) * HDIM + ks * 32 + lg * 8);

    bf16x8 ones;
    #pragma unroll
    for (int e = 0; e < 8; ++e) ones[e] = (bf16)1.0f;

    f32x4 oacc[4][2];          // [nd][mf] : O^T fragments (row=d, col=q)
    f32x4 lacc[2];             // L[q=l15] via ones-MFMA (all acc rows equal)
    #pragma unroll
    for (int mf = 0; mf < 2; ++mf) lacc[mf] = f32x4{0.f, 0.f, 0.f, 0.f};
    #pragma unroll
    for (int nd = 0; nd < 4; ++nd)
        #pragma unroll
        for (int mf = 0; mf < 2; ++mf)
            oacc[nd][mf] = f32x4{0.f, 0.f, 0.f, 0.f};

    char* Pw = (char*)Pl[w];
    const int l7 = l15 & 7;
    const int srow0 = tid >> 3;
    const int skc   = tid & 7;

    bf16x8 kr[2], vr[2];
    auto issue = [&](int j) {
        const int kk0 = j * 64;
        #pragma unroll
        for (int c = 0; c < 2; ++c) {
            int row = c * 32 + srow0;
            kr[c] = *(const bf16x8*)(Kp + (size_t)(kk0 + row) * HDIM + skc * 8);
            vr[c] = *(const bf16x8*)(Vp + (size_t)row * SEQL + kk0 + skc * 8);
        }
    };
    auto commit = [&](int b) {
        #pragma unroll
        for (int c = 0; c < 2; ++c) {
            int row = c * 32 + srow0;
            *(bf16x8*)((char*)Ks[b] + swz(row, skc)) = kr[c];
            *(bf16x8*)((char*)Vs[b] + swz(row, skc)) = vr[c];
        }
    };

    issue(0);
    commit(0);
    __syncthreads();

    for (int j = 0; j < njt; ++j) {
        const int kk0 = j * 64;
        const int buf = j & 1;
        const bool more = (j + 1 < njt);
        if (more) issue(j + 1);

        // ---- S^T = K Q^T : sacc[nf][mf], row=kv, col=q ----
        f32x4 sacc[4][2];
        #pragma unroll
        for (int nf = 0; nf < 4; ++nf)
            #pragma unroll
            for (int mf = 0; mf < 2; ++mf)
                sacc[nf][mf] = f32x4{0.f, 0.f, 0.f, 0.f};
        #pragma unroll
        for (int ks = 0; ks < 2; ++ks) {
            bf16x8 kf[4];
            #pragma unroll
            for (int nf = 0; nf < 4; ++nf)
                kf[nf] = *(const bf16x8*)((const char*)Ks[buf] + swz(nf * 16 + l15, ks * 4 + lg));
            #pragma unroll
            for (int nf = 0; nf < 4; ++nf)
                #pragma unroll
                for (int mf = 0; mf < 2; ++mf)
                    sacc[nf][mf] = __builtin_amdgcn_mfma_f32_16x16x32_bf16(
                        kf[nf], qf[mf][ks], sacc[nf][mf], 0, 0, 0);
        }

        // ---- P = exp2(S), mask, b64 write (r10 addressing, proven) ----
        const bool nm = (kk0 + 63 > q0);
        #pragma unroll
        for (int nf = 0; nf < 4; ++nf) {
            #pragma unroll
            for (int mf = 0; mf < 2; ++mf) {
                bf16x4 pb;
                #pragma unroll
                for (int r = 0; r < 4; ++r) {
                    float s = sacc[nf][mf][r];
                    if (nm) {
                        int kv = kk0 + nf * 16 + lg * 4 + r;
                        int qq = q0 + mf * 16 + l15;
                        if (kv > qq) s = -1.0e30f;
                    }
                    pb[r] = (bf16)exp2f(s);
                }
                *(bf16x4*)(Pw + (mf * 16 + l15) * 128
                              + (((2 * nf + (lg >> 1)) ^ l7) << 4) + (lg & 1) * 8) = pb;
            }
        }

        // ---- O^T += V^T P^T ; L += 1^T P^T (both matrix pipe) ----
        #pragma unroll
        for (int ks = 0; ks < 2; ++ks) {
            bf16x8 pf[2], vf[4];
            #pragma unroll
            for (int mf = 0; mf < 2; ++mf)
                pf[mf] = *(const bf16x8*)(Pw + (mf * 16 + l15) * 128
                                             + (((ks * 4 + lg) ^ l7) << 4));
            #pragma unroll
            for (int nd = 0; nd < 4; ++nd)
                vf[nd] = *(const bf16x8*)((const char*)Vs[buf] + swz(nd * 16 + l15, ks * 4 + lg));
            #pragma unroll
            for (int mf = 0; mf < 2; ++mf)
                lacc[mf] = __builtin_amdgcn_mfma_f32_16x16x32_bf16(
                    ones, pf[mf], lacc[mf], 0, 0, 0);
            #pragma unroll
            for (int nd = 0; nd < 4; ++nd)
                #pragma unroll
                for (int mf = 0; mf < 2; ++mf)
                    oacc[nd][mf] = __builtin_amdgcn_mfma_f32_16x16x32_bf16(
                        vf[nd], pf[mf], oacc[nd][mf], 0, 0, 0);
        }

        if (more) {
            commit(buf ^ 1);
            __syncthreads();
        }
    }

    // ---- epilogue: O = O^T / L (L[q] = lacc[mf][0], rows all equal) ----
    float inv[2] = {1.f / lacc[0][0], 1.f / lacc[1][0]};
    #pragma unroll
    for (int nd = 0; nd < 4; ++nd)
        #pragma unroll
        for (int mf = 0; mf < 2; ++mf) {
            bf16x4 o4;
            #pragma unroll
            for (int r = 0; r < 4; ++r)
                o4[r] = (bf16)(oacc[nd][mf][r] * inv[mf]);
            int s = q0 + mf * 16 + l15;
            int d = nd * 16 + lg * 4;
            *(bf16x4*)(Qp + (size_t)s * HDIM + d) = o4;
        }
}

// ---------------------------------------------------------------------------
// Kernel 3: output projection  out(f32) = O @ Wo^T  (r9 structure, kept).
// ---------------------------------------------------------------------------
__global__ __launch_bounds__(256, 2)
void oproj_kernel(const bf16* __restrict__ O, const bf16* __restrict__ Wob,
                  float* __restrict__ outp)
{
    __shared__ __align__(16) bf16 Bs[2][128 * 32];

    const int bm = (int)blockIdx.x * 128;
    const int bn = (int)blockIdx.y * 128;

    const int tid  = threadIdx.x;
    const int lane = tid & 63;
    const int w    = tid >> 6;
    const int l15  = lane & 15;
    const int lg   = lane >> 4;
    const int wm   = (w >> 1) * 64;
    const int wn   = (w & 1) * 64;

    f32x4 acc[4][4];
    #pragma unroll
    for (int mf = 0; mf < 4; ++mf)
        #pragma unroll
        for (int nf = 0; nf < 4; ++nf)
            acc[mf][nf] = f32x4{0.f, 0.f, 0.f, 0.f};

    const int c0  = w * 2;
    const int rp0 = lane >> 3;
    const int tt  = (lane & 7) ^ rp0;
    const int rgo = (tt >> 2) << 6;
    const int kq  = (tt & 3) * 8;

    auto stageB = [&](int t, int buf) {
        const int k0 = t * 32;
        #pragma unroll
        for (int i = 0; i < 2; ++i) {
            const int c  = c0 + i;
            const int rg = c * 8 + rp0 + rgo;
            gl_lds16(Wob + (size_t)(bn + rg) * DIMM + k0 + kq, &Bs[buf][c * 512]);
        }
    };

    auto loadA = [&](bf16x8 (&dst)[4], int t) {
        const int k0 = t * 32;
        #pragma unroll
        for (int mf = 0; mf < 4; ++mf) {
            int m = bm + wm + mf * 16 + l15;
            int b = m >> 11, s = m & 2047;
            int k = k0 + lg * 8;
            int h = k >> 6, dd = k & 63;
            dst[mf] = *(const bf16x8*)(O + ((size_t)((b * NHEADS + h) * SEQL + s)) * HDIM + dd);
        }
    };

    auto rd = [&](const bf16* base, int row) {
        return *(const bf16x8*)((const char*)base +
            (row & 63) * 128 + (((((row >> 6) << 2) | lg) ^ (row & 7)) << 4));
    };

    auto compute = [&](int buf, const bf16x8 (&af)[4]) {
        bf16x8 bfr[4];
        #pragma unroll
        for (int nf = 0; nf < 4; ++nf)
            bfr[nf] = rd(Bs[buf], wn + nf * 16 + l15);
        #pragma unroll
        for (int mf = 0; mf < 4; ++mf)
            #pragma unroll
            for (int nf = 0; nf < 4; ++nf)
                acc[mf][nf] = __builtin_amdgcn_mfma_f32_16x16x32_bf16(
                    af[mf], bfr[nf], acc[mf][nf], 0, 0, 0);
    };

    bf16x8 aA[4], aB[4];

    stageB(0, 0);
    __builtin_amdgcn_sched_barrier(0);
    loadA(aA, 0);
    __builtin_amdgcn_sched_barrier(0);

    // outstanding at wait = B(t)2 + A(t)4 + B(t+1)2 = 8 -> vmcnt(6) retires B(t)
    auto step = [&](bf16x8 (&cur)[4], bf16x8 (&nxt)[4], int t) {
        stageB(t + 1, (t + 1) & 1);
        __builtin_amdgcn_sched_barrier(0);
        asm volatile("s_waitcnt vmcnt(6)" ::: "memory");
        __builtin_amdgcn_s_barrier();
        __builtin_amdgcn_sched_barrier(0);
        loadA(nxt, t + 1);
        compute(t & 1, cur);
        __builtin_amdgcn_sched_barrier(0);
        __builtin_amdgcn_s_barrier();
    };

    #pragma unroll 1
    for (int tp = 0; tp < 15; ++tp) {
        step(aA, aB, 2 * tp);
        step(aB, aA, 2 * tp + 1);
    }
    step(aA, aB, 30);
    asm volatile("s_waitcnt vmcnt(0)" ::: "memory");
    __builtin_amdgcn_s_barrier();
    __builtin_amdgcn_sched_barrier(0);
    compute(1, aB);

    #pragma unroll
    for (int mf = 0; mf < 4; ++mf)
        #pragma unroll
        for (int nf = 0; nf < 4; ++nf) {
            int n = bn + wn + nf * 16 + l15;
            #pragma unroll
            for (int r = 0; r < 4; ++r) {
                int m = bm + wm + mf * 16 + lg * 4 + r;
                outp[(size_t)m * DIMM + n] = acc[mf][nf][r];
            }
        }
}

// ---------------------------------------------------------------------------
extern "C" void kernel_launch(void* const* d_in, const int* in_sizes, int n_in,
                              void* d_out, int out_size, void* d_ws, size_t ws_size,
                              hipStream_t stream)
{
    const float* x    = (const float*)d_in[0];
    const float* Wq   = (const float*)d_in[1];
    const float* Wk   = (const float*)d_in[2];
    const float* Wv   = (const float*)d_in[3];
    const float* Wo   = (const float*)d_in[4];
    const float* cosT = (const float*)d_in[5];
    const float* sinT = (const float*)d_in[6];

    const size_t NELEM = (size_t)MTOT * DIMM;   // 8.39M
    const size_t NW    = (size_t)DIMM * DIMM;   // 1.05M
    bf16* qb  = (bf16*)d_ws;          // 16.8 MB (becomes O after attn)
    bf16* kb  = qb + NELEM;           // 16.8 MB
    bf16* vT  = kb + NELEM;           // 16.8 MB
    bf16* xb  = vT + NELEM;           // 16.8 MB
    bf16* Wqb = xb + NELEM;           // 2.1 MB each
    bf16* Wkb = Wqb + NW;
    bf16* Wvb = Wkb + NW;
    bf16* Wob = Wvb + NW;             // high-water: 75.5 MB

    dim3 blk(256);
    // 12.58M elements / 8 per thread / 256 per block = 6144 blocks
    cvt_kernel<<<dim3(6144), blk, 0, stream>>>(x, Wq, Wk, Wv, Wo,
                                               xb, Wqb, Wkb, Wvb, Wob);

    qkv_kernel<<<dim3(512), blk, 0, stream>>>(xb, Wqb, Wkb, Wvb, cosT, sinT,
                                              qb, kb, vT);

    dim3 g2(NB * NHEADS, SEQL / 128);
    attn_kernel<<<g2, blk, 0, stream>>>(qb, kb, vT);

    dim3 g3(MTOT / 128, DIMM / 128);
    oproj_kernel<<<g3, blk, 0, stream>>>(qb, Wob, (float*)d_out);
}